// Round 1
// baseline (368.421 us; speedup 1.0000x reference)
//
#include <hip/hip_runtime.h>

// Problem geometry (from the reference):
//   input  "output": (T=402, 2, 256, 256) fp32  -> u = ch0, v = ch1
//   result: (f_u, f_v), each (400, 1, 252, 252) fp32, concatenated flat.
// f_u = u_t + u*u_x + v*u_y - (1/R) lap_u   (u_x = 4th-order deriv along H,
// f_v = v_t + u*v_x + v*v_y - (1/R) lap_v    u_y = along W; lap = 4th-order 9pt cross)

namespace {
constexpr int H = 256, W = 256;
constexpr int OWID = 252;              // output width/height
constexpr int NT = 400;                // output time steps
constexpr int PLANE   = H * W;         // 65536
constexpr int TSTRIDE = 2 * PLANE;     // 131072 floats per time step
constexpr int OPLANE  = OWID * OWID;   // 63504
constexpr size_t OUT_HALF = (size_t)NT * OPLANE;  // 25,401,600

// Constants (computed in double, rounded once to float — matches fp32 ref
// within ~1e-7 relative):
constexpr float DTF    = 10.0f / 200.0f;           // 0.05
constexpr float DXF    = 20.0f / 128.0f;           // 0.15625 (exact)
constexpr float INV2DT = (float)(1.0 / (2.0 * (double)DTF));   // 10.0
constexpr float C12DX  = (float)(1.0 / (12.0 * (double)DXF));  // 1/(12*DX)
constexpr float INVDX2 = (float)(1.0 / ((double)DXF * DXF));   // 40.96
constexpr float C43    = (float)(4.0 / 3.0);
constexpr float C112   = (float)(1.0 / 12.0);
constexpr float INVR   = (float)(1.0 / 200.0);

// Gather the full stencil for 4 consecutive pixels (centers at x0+2..x0+5).
// rowc points at row cy of the time-tt plane; rowm/rowp at row cy of tt-1/tt+1.
__device__ __forceinline__ void gather(const float* __restrict__ rowc,
                                       const float* __restrict__ rowm,
                                       const float* __restrict__ rowp,
                                       int x0,
                                       float r0[8], float hm2[4], float hm1[4],
                                       float hp1[4], float hp2[4],
                                       float tm[4], float tp[4]) {
    // Center row: 8 contiguous floats (covers W-direction stencil), 16B aligned.
    const float4 a = *reinterpret_cast<const float4*>(rowc + x0);
    const float4 b = *reinterpret_cast<const float4*>(rowc + x0 + 4);
    r0[0]=a.x; r0[1]=a.y; r0[2]=a.z; r0[3]=a.w;
    r0[4]=b.x; r0[5]=b.y; r0[6]=b.z; r0[7]=b.w;
    // Rows cy±1, cy±2 and time-neighbor centers: 4 floats at x0+2 (8B aligned).
    auto ld4 = [](const float* __restrict__ p, float d[4]) {
        const float2 u = *reinterpret_cast<const float2*>(p);
        const float2 v = *reinterpret_cast<const float2*>(p + 2);
        d[0]=u.x; d[1]=u.y; d[2]=v.x; d[3]=v.y;
    };
    ld4(rowc - 2*W + x0 + 2, hm2);
    ld4(rowc - 1*W + x0 + 2, hm1);
    ld4(rowc + 1*W + x0 + 2, hp1);
    ld4(rowc + 2*W + x0 + 2, hp2);
    ld4(rowm + x0 + 2, tm);
    ld4(rowp + x0 + 2, tp);
}
} // namespace

__global__ __launch_bounds__(256)
void pde_residual_kernel(const float* __restrict__ in, float* __restrict__ out) {
    const int qx = threadIdx.x;                    // quad index along W, 0..62 used
    const int y  = blockIdx.y * blockDim.y + threadIdx.y;  // 0..251
    const int t  = blockIdx.z;                     // 0..399
    if (qx >= (OWID / 4)) return;                  // 63 quads per row
    const int x0 = qx * 4;
    const int cy = y + 2;                          // input row of the center
    const int tt = t + 1;                          // input time of the center

    const float* urow  = in + (size_t)tt * TSTRIDE + cy * W;   // u, time tt
    const float* vrow  = urow + PLANE;                          // v, time tt
    const float* umrow = urow - TSTRIDE;                        // u, tt-1
    const float* uprow = urow + TSTRIDE;                        // u, tt+1
    const float* vmrow = vrow - TSTRIDE;
    const float* vprow = vrow + TSTRIDE;

    float ur0[8], uhm2[4], uhm1[4], uhp1[4], uhp2[4], utm[4], utp[4];
    float vr0[8], vhm2[4], vhm1[4], vhp1[4], vhp2[4], vtm[4], vtp[4];
    gather(urow, umrow, uprow, x0, ur0, uhm2, uhm1, uhp1, uhp2, utm, utp);
    gather(vrow, vmrow, vprow, x0, vr0, vhm2, vhm1, vhp1, vhp2, vtm, vtp);

    float fu[4], fv[4];
    #pragma unroll
    for (int i = 0; i < 4; ++i) {
        const float uc = ur0[i + 2];
        const float vc = vr0[i + 2];
        // 4th-order first derivatives. "x" = H axis (PART_X), "y" = W axis.
        const float u_x = (uhm2[i] - 8.f*uhm1[i] + 8.f*uhp1[i] - uhp2[i]) * C12DX;
        const float v_x = (vhm2[i] - 8.f*vhm1[i] + 8.f*vhp1[i] - vhp2[i]) * C12DX;
        const float u_y = (ur0[i] - 8.f*ur0[i+1] + 8.f*ur0[i+3] - ur0[i+4]) * C12DX;
        const float v_y = (vr0[i] - 8.f*vr0[i+1] + 8.f*vr0[i+3] - vr0[i+4]) * C12DX;
        // 4th-order 9-point cross Laplacian.
        const float u_lap = (C43 * (ur0[i+1] + ur0[i+3] + uhm1[i] + uhp1[i])
                           - C112 * (ur0[i]   + ur0[i+4] + uhm2[i] + uhp2[i])
                           - 5.f * uc) * INVDX2;
        const float v_lap = (C43 * (vr0[i+1] + vr0[i+3] + vhm1[i] + vhp1[i])
                           - C112 * (vr0[i]   + vr0[i+4] + vhm2[i] + vhp2[i])
                           - 5.f * vc) * INVDX2;
        // Central time derivative.
        const float u_t = (utp[i] - utm[i]) * INV2DT;
        const float v_t = (vtp[i] - vtm[i]) * INV2DT;

        fu[i] = u_t + uc * u_x + vc * u_y - INVR * u_lap;
        fv[i] = v_t + uc * v_x + vc * v_y - INVR * v_lap;
    }

    float* po = out + (size_t)t * OPLANE + (size_t)y * OWID + x0;
    *reinterpret_cast<float4*>(po)            = make_float4(fu[0], fu[1], fu[2], fu[3]);
    *reinterpret_cast<float4*>(po + OUT_HALF) = make_float4(fv[0], fv[1], fv[2], fv[3]);
}

extern "C" void kernel_launch(void* const* d_in, const int* in_sizes, int n_in,
                              void* d_out, int out_size, void* d_ws, size_t ws_size,
                              hipStream_t stream) {
    (void)in_sizes; (void)n_in; (void)d_ws; (void)ws_size; (void)out_size;
    const float* in = (const float*)d_in[0];
    float* out = (float*)d_out;

    // block (64,4): 63 active quads × 4 rows = one 252-wide × 4-tall tile.
    // grid y = 252/4 = 63 row-tiles, z = 400 time steps. Consecutive blocks
    // sweep y within a time slice -> co-resident blocks cluster in t for
    // L2/LLC reuse of the tt±1 center reads and row halos.
    dim3 block(64, 4, 1);
    dim3 grid(1, OWID / 4, NT);
    pde_residual_kernel<<<grid, block, 0, stream>>>(in, out);
}